// Round 2
// baseline (404.472 us; speedup 1.0000x reference)
//
#include <hip/hip_runtime.h>
#include <hip/hip_bf16.h>
#include <hip/hip_cooperative_groups.h>

namespace cg = cooperative_groups;

typedef __bf16 bf16x8 __attribute__((ext_vector_type(8)));
typedef __bf16 bf16x4 __attribute__((ext_vector_type(4)));
typedef float  f32x4  __attribute__((ext_vector_type(4)));
typedef float  f32x2  __attribute__((ext_vector_type(2)));

#define FP8_MAX 448.0f
#define M 32
#define N 12288
#define K 4096
#define NB (N / 16)   // 768 blocks, 16 output cols each (merged path)
#define NBLK 2048     // fallback amax grid

// quantize 4 fp32 weights -> fp8 e4m3fn (HW RNE) -> dequant -> bf16
__device__ inline bf16x4 quant4(const f32x4 w, float scale, float recip) {
    float x0 = fminf(fmaxf(w[0] * scale, -FP8_MAX), FP8_MAX);
    float x1 = fminf(fmaxf(w[1] * scale, -FP8_MAX), FP8_MAX);
    float x2 = fminf(fmaxf(w[2] * scale, -FP8_MAX), FP8_MAX);
    float x3 = fminf(fmaxf(w[3] * scale, -FP8_MAX), FP8_MAX);
    int p01 = __builtin_amdgcn_cvt_pk_fp8_f32(x0, x1, 0, false);
    int p23 = __builtin_amdgcn_cvt_pk_fp8_f32(x2, x3, 0, false);
    f32x2 d01 = __builtin_amdgcn_cvt_pk_f32_fp8(p01, false);
    f32x2 d23 = __builtin_amdgcn_cvt_pk_f32_fp8(p23, false);
    bf16x4 r;
    r[0] = (__bf16)(d01.x * recip);
    r[1] = (__bf16)(d01.y * recip);
    r[2] = (__bf16)(d23.x * recip);
    r[3] = (__bf16)(d23.y * recip);
    return r;
}

// ---------------- Merged cooperative kernel ----------------
// Phase 1: GRID-STRIDE amax over all of W (768*256 threads * 64 iters covers
//          the 12.58M float4 exactly; each iteration the grid reads one
//          contiguous 3 MiB span -> all HBM channels active every instant).
//          Round 1 post-mortem: per-block contiguous 256 KiB slices put every
//          block on the same channel phase in lockstep -> 1.1 TB/s. Grid-stride
//          is the proven ~6 TB/s pattern. Per-block locality is worthless here
//          anyway (phase 2 is L3-fed; working set >> L2).
// grid.sync()
// Phase 2: reduce 768 slots -> scale, then streamed quantize + MFMA GEMM
//          (identical structure to the verified 2-kernel version).
__global__ __launch_bounds__(256, 3) void fused_all(const float* __restrict__ W,
                                                    const float* __restrict__ A,
                                                    const float* __restrict__ bias,
                                                    float* __restrict__ slots,
                                                    __bf16* __restrict__ A_sw,
                                                    float* __restrict__ C) {
    const int b    = blockIdx.x;
    const int t    = threadIdx.x;
    const int lane = t & 63;
    const int wave = t >> 6;

    // ---- Phase 1a: A fp32 -> bf16 fragment pre-swizzle (16384 slots) ----
    if (b < 64) {
        int tid  = b * 256 + t;                      // 0..16383
        int l    = tid & 63;
        int mt   = (tid >> 6) & 1;
        int s    = tid >> 7;                         // 0..127
        int row  = mt * 16 + (l & 15);
        int kk   = s * 32 + (l >> 4) * 8;
        const float* src = A + row * K + kk;
        f32x4 a0 = *(const f32x4*)src;
        f32x4 a1 = *(const f32x4*)(src + 4);
        bf16x8 p;
        p[0] = (__bf16)a0[0]; p[1] = (__bf16)a0[1];
        p[2] = (__bf16)a0[2]; p[3] = (__bf16)a0[3];
        p[4] = (__bf16)a1[0]; p[5] = (__bf16)a1[1];
        p[6] = (__bf16)a1[2]; p[7] = (__bf16)a1[3];
        *(bf16x8*)(A_sw + (size_t)tid * 8) = p;
    }

    // ---- Phase 1b: grid-stride amax over W (exactly 64 iters/thread) ----
    {
        const f32x4* W4 = (const f32x4*)W;           // 12582912 float4
        const int idx = b * 256 + t;                 // 0..196607
        float m = 0.0f;
#pragma unroll 8
        for (int i = 0; i < 64; ++i) {
            f32x4 v = W4[idx + i * (NB * 256)];
            m = fmaxf(m, fmaxf(fmaxf(fabsf(v[0]), fabsf(v[1])),
                               fmaxf(fabsf(v[2]), fabsf(v[3]))));
        }
#pragma unroll
        for (int off = 32; off > 0; off >>= 1)
            m = fmaxf(m, __shfl_xor(m, off, 64));
        __shared__ float smax[4];
        if (lane == 0) smax[wave] = m;
        __syncthreads();
        if (t == 0)
            slots[b] = fmaxf(fmaxf(smax[0], smax[1]), fmaxf(smax[2], smax[3]));
    }

    cg::this_grid().sync();

    // ---- Phase 2a: reduce 768 slot maxima -> global scale (every wave) ----
    const f32x4* sl4 = (const f32x4*)slots;          // 192 float4
    float g = 0.0f;
#pragma unroll
    for (int i = 0; i < 3; ++i) {
        f32x4 v = sl4[lane + i * 64];
        g = fmaxf(fmaxf(g, fmaxf(v[0], v[1])), fmaxf(v[2], v[3]));
    }
#pragma unroll
    for (int off = 32; off > 0; off >>= 1)
        g = fmaxf(g, __shfl_xor(g, off, 64));
    float amax  = fmaxf(g, 1e-12f);
    float scale = FP8_MAX / amax;
    float recip = 1.0f / scale;

    // ---- Phase 2b: streamed quantize + GEMM, in-block K-split ----
    const int n0   = b * 16;
    const int col  = lane & 15;
    const int quad = lane >> 4;

    const float*  wrow = W + (size_t)(n0 + col) * K + quad * 8;  // B-frag base
    const __bf16* ap   = A_sw + (size_t)lane * 8;                // A-frag base

    f32x4 acc0 = {0.f, 0.f, 0.f, 0.f};
    f32x4 acc1 = {0.f, 0.f, 0.f, 0.f};

    const int s0 = wave * (K / 32 / 4);              // 32 s-iters per wave
#pragma unroll 4
    for (int si = 0; si < K / 32 / 4; ++si) {
        const int s = s0 + si;
        f32x4 w0 = *(const f32x4*)(wrow + s * 32);
        f32x4 w1 = *(const f32x4*)(wrow + s * 32 + 4);
        union { bf16x8 v; bf16x4 h[2]; } bb;
        bb.h[0] = quant4(w0, scale, recip);
        bb.h[1] = quant4(w1, scale, recip);
        bf16x8 a0 = *(const bf16x8*)(ap + s * 1024);        // slot (s, mt=0)
        bf16x8 a1 = *(const bf16x8*)(ap + s * 1024 + 512);  // slot (s, mt=1)
        acc0 = __builtin_amdgcn_mfma_f32_16x16x32_bf16(a0, bb.v, acc0, 0, 0, 0);
        acc1 = __builtin_amdgcn_mfma_f32_16x16x32_bf16(a1, bb.v, acc1, 0, 0, 0);
    }

    // 4-way partial reduction: waves 1..3 park partials in LDS; wave 0 sums.
    __shared__ float red[3][64][8];                  // 6 KB
    if (wave != 0) {
        float* dst = &red[wave - 1][lane][0];
#pragma unroll
        for (int r = 0; r < 4; ++r) { dst[r] = acc0[r]; dst[4 + r] = acc1[r]; }
    }
    __syncthreads();
    if (wave == 0) {
        const int gn = n0 + col;
        const float bv = bias[gn];
#pragma unroll
        for (int r = 0; r < 4; ++r) {
            float v0 = acc0[r] + red[0][lane][r]     + red[1][lane][r]     + red[2][lane][r];
            float v1 = acc1[r] + red[0][lane][4 + r] + red[1][lane][4 + r] + red[2][lane][4 + r];
            // C/D layout: col=lane&15, row=quad*4+r (validated previously)
            C[(quad * 4 + r) * N + gn]      = v0 + bv;
            C[(16 + quad * 4 + r) * N + gn] = v1 + bv;
        }
    }
}

// ---------------- Fallback path (identical to verified 2-kernel version) ----------
__global__ __launch_bounds__(256) void amax_pack(const float4* __restrict__ W4,
                                                 const float* __restrict__ A,
                                                 float* __restrict__ slots,
                                                 __bf16* __restrict__ A_sw) {
    if (blockIdx.x < 64) {
        int tid  = blockIdx.x * 256 + threadIdx.x;   // 0..16383
        int lane = tid & 63;
        int mt   = (tid >> 6) & 1;
        int s    = tid >> 7;                         // 0..127
        int row  = mt * 16 + (lane & 15);
        int kk   = s * 32 + (lane >> 4) * 8;
        const float* src = A + row * K + kk;
        f32x4 a0 = *(const f32x4*)src;
        f32x4 a1 = *(const f32x4*)(src + 4);
        bf16x8 p;
        p[0] = (__bf16)a0[0]; p[1] = (__bf16)a0[1];
        p[2] = (__bf16)a0[2]; p[3] = (__bf16)a0[3];
        p[4] = (__bf16)a1[0]; p[5] = (__bf16)a1[1];
        p[6] = (__bf16)a1[2]; p[7] = (__bf16)a1[3];
        *(bf16x8*)(A_sw + (size_t)tid * 8) = p;
    }
    const int n4 = (N * K) / 4;
    int idx = blockIdx.x * 256 + threadIdx.x;
    int stride = gridDim.x * 256;
    float m = 0.0f;
    for (int i = idx; i < n4; i += stride) {
        float4 v = W4[i];
        m = fmaxf(m, fabsf(v.x)); m = fmaxf(m, fabsf(v.y));
        m = fmaxf(m, fabsf(v.z)); m = fmaxf(m, fabsf(v.w));
    }
#pragma unroll
    for (int off = 32; off > 0; off >>= 1)
        m = fmaxf(m, __shfl_down(m, off, 64));
    __shared__ float smax[4];
    if ((threadIdx.x & 63) == 0) smax[threadIdx.x >> 6] = m;
    __syncthreads();
    if (threadIdx.x == 0)
        slots[blockIdx.x] = fmaxf(fmaxf(smax[0], smax[1]), fmaxf(smax[2], smax[3]));
}

__global__ __launch_bounds__(256) void fused_gemm(const float* __restrict__ W,
                                                  const __bf16* __restrict__ A_sw,
                                                  const float* __restrict__ bias,
                                                  const float* __restrict__ slots,
                                                  float* __restrict__ C) {
    const int n0 = blockIdx.x * 16;
    const int t = threadIdx.x;
    const int lane = t & 63;
    const int wave = t >> 6;
    const int col = lane & 15;
    const int quad = lane >> 4;

    const f32x4* sl4 = (const f32x4*)slots;          // 512 float4
    float m = 0.0f;
#pragma unroll
    for (int i = 0; i < 8; ++i) {
        f32x4 v = sl4[lane + i * 64];
        m = fmaxf(fmaxf(m, fmaxf(v[0], v[1])), fmaxf(v[2], v[3]));
    }
#pragma unroll
    for (int off = 32; off > 0; off >>= 1)
        m = fmaxf(m, __shfl_xor(m, off, 64));
    float amax  = fmaxf(m, 1e-12f);
    float scale = FP8_MAX / amax;
    float recip = 1.0f / scale;

    const float*  wrow = W + (size_t)(n0 + col) * K + quad * 8;
    const __bf16* ap   = A_sw + (size_t)lane * 8;

    f32x4 acc0 = {0.f, 0.f, 0.f, 0.f};
    f32x4 acc1 = {0.f, 0.f, 0.f, 0.f};

    const int s0 = wave * (K / 32 / 4);
#pragma unroll 4
    for (int si = 0; si < K / 32 / 4; ++si) {
        const int s = s0 + si;
        f32x4 w0 = *(const f32x4*)(wrow + s * 32);
        f32x4 w1 = *(const f32x4*)(wrow + s * 32 + 4);
        union { bf16x8 v; bf16x4 h[2]; } bb;
        bb.h[0] = quant4(w0, scale, recip);
        bb.h[1] = quant4(w1, scale, recip);
        bf16x8 a0 = *(const bf16x8*)(ap + s * 1024);
        bf16x8 a1 = *(const bf16x8*)(ap + s * 1024 + 512);
        acc0 = __builtin_amdgcn_mfma_f32_16x16x32_bf16(a0, bb.v, acc0, 0, 0, 0);
        acc1 = __builtin_amdgcn_mfma_f32_16x16x32_bf16(a1, bb.v, acc1, 0, 0, 0);
    }

    __shared__ float red[3][64][8];
    if (wave != 0) {
        float* dst = &red[wave - 1][lane][0];
#pragma unroll
        for (int r = 0; r < 4; ++r) { dst[r] = acc0[r]; dst[4 + r] = acc1[r]; }
    }
    __syncthreads();
    if (wave == 0) {
        const int gn = n0 + col;
        const float bv = bias[gn];
#pragma unroll
        for (int r = 0; r < 4; ++r) {
            float v0 = acc0[r] + red[0][lane][r]     + red[1][lane][r]     + red[2][lane][r];
            float v1 = acc1[r] + red[0][lane][4 + r] + red[1][lane][4 + r] + red[2][lane][4 + r];
            C[(quad * 4 + r) * N + gn]      = v0 + bv;
            C[(16 + quad * 4 + r) * N + gn] = v1 + bv;
        }
    }
}

extern "C" void kernel_launch(void* const* d_in, const int* in_sizes, int n_in,
                              void* d_out, int out_size, void* d_ws, size_t ws_size,
                              hipStream_t stream) {
    const float* A    = (const float*)d_in[0];
    const float* W    = (const float*)d_in[1];
    const float* bias = (const float*)d_in[2];
    float* C = (float*)d_out;
    float*  slots = (float*)d_ws;                    // ≤2048 floats (8 KB)
    __bf16* A_sw  = (__bf16*)((char*)d_ws + 8192);   // 256 KB, rewritten every launch

    void* args[6];
    args[0] = (void*)&W;
    args[1] = (void*)&A;
    args[2] = (void*)&bias;
    args[3] = (void*)&slots;
    args[4] = (void*)&A_sw;
    args[5] = (void*)&C;
    hipError_t e = hipLaunchCooperativeKernel((const void*)fused_all,
                                              dim3(NB), dim3(256), args, 0, stream);
    if (e != hipSuccess) {
        // cooperative launch rejected (e.g. under capture) -> verified 2-kernel path
        (void)hipGetLastError();
        amax_pack<<<NBLK, 256, 0, stream>>>((const float4*)W, A, slots, A_sw);
        fused_gemm<<<N / 16, 256, 0, stream>>>(W, A_sw, bias, slots, C);
    }
}

// Round 4
// 305.909 us; speedup vs baseline: 1.3222x; 1.3222x over previous
//
#include <hip/hip_runtime.h>
#include <hip/hip_bf16.h>

typedef __bf16 bf16x8 __attribute__((ext_vector_type(8)));
typedef __bf16 bf16x4 __attribute__((ext_vector_type(4)));
typedef float  f32x4  __attribute__((ext_vector_type(4)));
typedef float  f32x2  __attribute__((ext_vector_type(2)));

#define FP8_MAX 448.0f
#define M 32
#define N 12288
#define K 4096
#define NBLK 2048   // amax_pack grid size == slot count

// ---------------- Pass 1: per-block amax over |W| + A bf16 pre-swizzle ----------
// (verified round-0 kernel, unchanged: grid-stride streams W at ~6 TB/s)
__global__ __launch_bounds__(256) void amax_pack(const float4* __restrict__ W4,
                                                 const float* __restrict__ A,
                                                 float* __restrict__ slots,
                                                 __bf16* __restrict__ A_sw) {
    if (blockIdx.x < 64) {
        int tid  = blockIdx.x * 256 + threadIdx.x;   // 0..16383
        int lane = tid & 63;
        int mt   = (tid >> 6) & 1;
        int s    = tid >> 7;                         // 0..127
        int row  = mt * 16 + (lane & 15);
        int kk   = s * 32 + (lane >> 4) * 8;
        const float* src = A + row * K + kk;
        f32x4 a0 = *(const f32x4*)src;
        f32x4 a1 = *(const f32x4*)(src + 4);
        bf16x8 p;
        p[0] = (__bf16)a0[0]; p[1] = (__bf16)a0[1];
        p[2] = (__bf16)a0[2]; p[3] = (__bf16)a0[3];
        p[4] = (__bf16)a1[0]; p[5] = (__bf16)a1[1];
        p[6] = (__bf16)a1[2]; p[7] = (__bf16)a1[3];
        *(bf16x8*)(A_sw + (size_t)tid * 8) = p;
    }
    const int n4 = (N * K) / 4;                      // 12582912 float4
    int idx = blockIdx.x * 256 + threadIdx.x;
    int stride = gridDim.x * 256;
    float m = 0.0f;
    for (int i = idx; i < n4; i += stride) {
        float4 v = W4[i];
        m = fmaxf(m, fabsf(v.x)); m = fmaxf(m, fabsf(v.y));
        m = fmaxf(m, fabsf(v.z)); m = fmaxf(m, fabsf(v.w));
    }
#pragma unroll
    for (int off = 32; off > 0; off >>= 1)
        m = fmaxf(m, __shfl_down(m, off, 64));
    __shared__ float smax[4];
    if ((threadIdx.x & 63) == 0) smax[threadIdx.x >> 6] = m;
    __syncthreads();
    if (threadIdx.x == 0)
        slots[blockIdx.x] = fmaxf(fmaxf(smax[0], smax[1]), fmaxf(smax[2], smax[3]));
}

// quantize 4 fp32 weights -> fp8 e4m3fn (HW RNE) -> dequant -> bf16
__device__ inline bf16x4 quant4(const f32x4 w, float scale, float recip) {
    float x0 = fminf(fmaxf(w[0] * scale, -FP8_MAX), FP8_MAX);
    float x1 = fminf(fmaxf(w[1] * scale, -FP8_MAX), FP8_MAX);
    float x2 = fminf(fmaxf(w[2] * scale, -FP8_MAX), FP8_MAX);
    float x3 = fminf(fmaxf(w[3] * scale, -FP8_MAX), FP8_MAX);
    int p01 = __builtin_amdgcn_cvt_pk_fp8_f32(x0, x1, 0, false);
    int p23 = __builtin_amdgcn_cvt_pk_fp8_f32(x2, x3, 0, false);
    f32x2 d01 = __builtin_amdgcn_cvt_pk_f32_fp8(p01, false);
    f32x2 d23 = __builtin_amdgcn_cvt_pk_f32_fp8(p23, false);
    bf16x4 r;
    r[0] = (__bf16)(d01.x * recip);
    r[1] = (__bf16)(d01.y * recip);
    r[2] = (__bf16)(d23.x * recip);
    r[3] = (__bf16)(d23.y * recip);
    return r;
}

// ---------------- Pass 2: streamed quantize + GEMM, in-block K-split ----------
// 512 threads / 8 waves per block (K split 8 ways, 16 s-iters per wave)
// -> 24 waves/CU, 2x outstanding loads, to lift the L3-hit read rate of W.
// Fragment math, A_sw layout, and C-write identical to the verified version;
// only the LDS partial reduction widens from 4-way to 8-way.
__global__ __launch_bounds__(512) void fused_gemm(const float* __restrict__ W,
                                                  const __bf16* __restrict__ A_sw,
                                                  const float* __restrict__ bias,
                                                  const float* __restrict__ slots,
                                                  float* __restrict__ C) {
    const int n0 = blockIdx.x * 16;
    const int t = threadIdx.x;
    const int lane = t & 63;
    const int wave = t >> 6;                         // 0..7
    const int col = lane & 15;
    const int quad = lane >> 4;

    // reduce 2048 slot maxima -> global amax (every wave computes it)
    const f32x4* sl4 = (const f32x4*)slots;          // 512 float4
    float m = 0.0f;
#pragma unroll
    for (int i = 0; i < 8; ++i) {
        f32x4 v = sl4[lane + i * 64];
        m = fmaxf(fmaxf(m, fmaxf(v[0], v[1])), fmaxf(v[2], v[3]));
    }
#pragma unroll
    for (int off = 32; off > 0; off >>= 1)
        m = fmaxf(m, __shfl_xor(m, off, 64));
    float amax  = fmaxf(m, 1e-12f);
    float scale = FP8_MAX / amax;
    float recip = 1.0f / scale;

    const float*  wrow = W + (size_t)(n0 + col) * K + quad * 8;  // B-frag base
    const __bf16* ap   = A_sw + (size_t)lane * 8;                // A-frag base

    f32x4 acc0 = {0.f, 0.f, 0.f, 0.f};
    f32x4 acc1 = {0.f, 0.f, 0.f, 0.f};

    const int s0 = wave * (K / 32 / 8);              // 16 s-iters per wave
#pragma unroll 4
    for (int si = 0; si < K / 32 / 8; ++si) {
        const int s = s0 + si;
        f32x4 w0 = *(const f32x4*)(wrow + s * 32);
        f32x4 w1 = *(const f32x4*)(wrow + s * 32 + 4);
        union { bf16x8 v; bf16x4 h[2]; } b;
        b.h[0] = quant4(w0, scale, recip);
        b.h[1] = quant4(w1, scale, recip);
        bf16x8 a0 = *(const bf16x8*)(ap + s * 1024);        // slot (s, mt=0)
        bf16x8 a1 = *(const bf16x8*)(ap + s * 1024 + 512);  // slot (s, mt=1)
        acc0 = __builtin_amdgcn_mfma_f32_16x16x32_bf16(a0, b.v, acc0, 0, 0, 0);
        acc1 = __builtin_amdgcn_mfma_f32_16x16x32_bf16(a1, b.v, acc1, 0, 0, 0);
    }

    // 8-way partial reduction: waves 1..7 park partials in LDS; wave 0 sums.
    __shared__ float red[7][64][8];                  // 14 KB
    if (wave != 0) {
        float* dst = &red[wave - 1][lane][0];
#pragma unroll
        for (int r = 0; r < 4; ++r) { dst[r] = acc0[r]; dst[4 + r] = acc1[r]; }
    }
    __syncthreads();
    if (wave == 0) {
        const int gn = n0 + col;
        const float bv = bias[gn];
#pragma unroll
        for (int r = 0; r < 4; ++r) {
            float v0 = acc0[r];
            float v1 = acc1[r];
#pragma unroll
            for (int j = 0; j < 7; ++j) {
                v0 += red[j][lane][r];
                v1 += red[j][lane][4 + r];
            }
            // C/D layout: col=lane&15, row=quad*4+r (validated previously)
            C[(quad * 4 + r) * N + gn]      = v0 + bv;
            C[(16 + quad * 4 + r) * N + gn] = v1 + bv;
        }
    }
}

extern "C" void kernel_launch(void* const* d_in, const int* in_sizes, int n_in,
                              void* d_out, int out_size, void* d_ws, size_t ws_size,
                              hipStream_t stream) {
    const float* A    = (const float*)d_in[0];
    const float* W    = (const float*)d_in[1];
    const float* bias = (const float*)d_in[2];
    float* C = (float*)d_out;
    float*  slots = (float*)d_ws;                    // 2048 floats (8 KB)
    __bf16* A_sw  = (__bf16*)((char*)d_ws + 8192);   // 256 KB, rewritten every launch

    amax_pack<<<NBLK, 256, 0, stream>>>((const float4*)W, A, slots, A_sw);
    fused_gemm<<<N / 16, 512, 0, stream>>>(W, A_sw, bias, slots, C);
}